// Round 18
// baseline (445.252 us; speedup 1.0000x reference)
//
#include <hip/hip_runtime.h>
#include <math.h>

// ---------- config ----------
#define T_TOK 4096
#define DIM   2048
#define NEXP  32
#define TOPK  4
#define CAP   160          // ceil(1.25*4096/32)
#define ECAP  (NEXP*CAP)   // 5120
#define ISZ   1024         // moe intermediate
#define ISH   2048         // shared intermediate (I*NSH)

typedef short bf16x8 __attribute__((ext_vector_type(8)));
typedef float f32x4  __attribute__((ext_vector_type(4)));

__device__ __forceinline__ unsigned int f2bf(float f){
  union { float f; unsigned int u; } v; v.f = f;
  return (v.u + 0x7fffu + ((v.u >> 16) & 1u)) >> 16;   // RNE
}

// async global->LDS, 16B/lane; LDS base wave-uniform (HW adds lane*16), global addr per-lane
#define GLOAD16(g, l) __builtin_amdgcn_global_load_lds( \
    (const __attribute__((address_space(1))) unsigned int*)(g), \
    (__attribute__((address_space(3))) unsigned int*)(l), 16, 0, 0)

// ---------- router: fp32 fast-path logits + certified margins; fp64 fallback ----------
__global__ __launch_bounds__(256) void router_k(const float* __restrict__ x,
                                                const float* __restrict__ rw,
                                                const float* __restrict__ eb,
                                                int* __restrict__ tki,
                                                float* __restrict__ tkw,
                                                unsigned short* __restrict__ xbf,
                                                const float* __restrict__ sg,
                                                const float* __restrict__ su,
                                                const float* __restrict__ sd,
                                                unsigned short* __restrict__ sgb,
                                                unsigned short* __restrict__ sub_,
                                                unsigned short* __restrict__ sdb){
  __shared__ float xs[4][DIM];
  __shared__ float lsh[4][NEXP];   // fp32 logits
  __shared__ float wsh[NEXP];      // ||w_e||^2
  __shared__ float xq[4];          // ||x_t||^2
  const int tb = blockIdx.x * 4;
  const int tid = threadIdx.x;
  for (int i = tid; i < 4*(DIM/4); i += 256){
    int t = i >> 9, c = (i & 511) << 2;
    float4 f = *(const float4*)&x[(size_t)(tb + t)*DIM + c];
    *(float4*)&xs[t][c] = f;
    uint2 w;
    w.x = f2bf(f.x) | (f2bf(f.y) << 16);
    w.y = f2bf(f.z) | (f2bf(f.w) << 16);
    *(uint2*)&xbf[(size_t)(tb + t)*DIM + c] = w;     // fused x -> bf16
  }
  __syncthreads();
  const int lane = tid & 63, wv = tid >> 6;

  // ---- fp32 dot phase: wave wv = experts wv*8..+7; float4-vectorized, unrolled ----
  for (int ei = 0; ei < 8; ++ei){
    const int e = wv*8 + ei;
    const float4* wr4 = (const float4*)&rw[(size_t)e*DIM];
    float a0=0.f,a1=0.f,a2=0.f,a3=0.f,w2=0.f;
    float x20=0.f,x21=0.f,x22=0.f,x23=0.f;
    const bool doX2 = (wv == 0) && (ei == 0);
    #pragma unroll
    for (int it = 0; it < 8; ++it){
      const int d4 = it*64 + lane;
      float4 w4 = wr4[d4];
      float4 v0 = *(const float4*)&xs[0][d4*4];
      float4 v1 = *(const float4*)&xs[1][d4*4];
      float4 v2 = *(const float4*)&xs[2][d4*4];
      float4 v3 = *(const float4*)&xs[3][d4*4];
      a0 = fmaf(v0.x,w4.x,fmaf(v0.y,w4.y,fmaf(v0.z,w4.z,fmaf(v0.w,w4.w,a0))));
      a1 = fmaf(v1.x,w4.x,fmaf(v1.y,w4.y,fmaf(v1.z,w4.z,fmaf(v1.w,w4.w,a1))));
      a2 = fmaf(v2.x,w4.x,fmaf(v2.y,w4.y,fmaf(v2.z,w4.z,fmaf(v2.w,w4.w,a2))));
      a3 = fmaf(v3.x,w4.x,fmaf(v3.y,w4.y,fmaf(v3.z,w4.z,fmaf(v3.w,w4.w,a3))));
      w2 = fmaf(w4.x,w4.x,fmaf(w4.y,w4.y,fmaf(w4.z,w4.z,fmaf(w4.w,w4.w,w2))));
      if (doX2){
        x20 = fmaf(v0.x,v0.x,fmaf(v0.y,v0.y,fmaf(v0.z,v0.z,fmaf(v0.w,v0.w,x20))));
        x21 = fmaf(v1.x,v1.x,fmaf(v1.y,v1.y,fmaf(v1.z,v1.z,fmaf(v1.w,v1.w,x21))));
        x22 = fmaf(v2.x,v2.x,fmaf(v2.y,v2.y,fmaf(v2.z,v2.z,fmaf(v2.w,v2.w,x22))));
        x23 = fmaf(v3.x,v3.x,fmaf(v3.y,v3.y,fmaf(v3.z,v3.z,fmaf(v3.w,v3.w,x23))));
      }
    }
    #pragma unroll
    for (int off = 32; off; off >>= 1){
      a0 += __shfl_down(a0, off); a1 += __shfl_down(a1, off);
      a2 += __shfl_down(a2, off); a3 += __shfl_down(a3, off);
      w2 += __shfl_down(w2, off);
      if (doX2){
        x20 += __shfl_down(x20, off); x21 += __shfl_down(x21, off);
        x22 += __shfl_down(x22, off); x23 += __shfl_down(x23, off);
      }
    }
    if (lane == 0){
      lsh[0][e] = a0; lsh[1][e] = a1; lsh[2][e] = a2; lsh[3][e] = a3;
      wsh[e] = w2;
      if (doX2){ xq[0]=x20; xq[1]=x21; xq[2]=x22; xq[3]=x23; }
    }
  }
  __syncthreads();

  // ---- wave-parallel top-k with certified margins: wave wv = token wv; lane e = expert ----
  {
    const int t = wv;
    const int e = lane & 31;
    const float Lf = lsh[t][e];
    float errS = 0.25f * sqrtf(xq[t]) * sqrtf(wsh[e]) * 6e-6f;  // score-space bound
    #pragma unroll
    for (int off = 16; off; off >>= 1)
      errS = fmaxf(errS, __shfl_xor(errS, off));

    double s  = 1.0 / (1.0 + exp(-(double)Lf));
    double sc = s + (double)eb[e];

    int idxr[4]; double svalr[4]; double wsum;
    double g23, g34, g45;
    auto decide = [&](double s_, double sc_){
      const int gb = e & ~3;
      double b0 = __shfl(sc_, gb+0), b1 = __shfl(sc_, gb+1);
      double b2 = __shfl(sc_, gb+2), b3 = __shfl(sc_, gb+3);
      double p = fmax(b0,b1), q = fmin(b0,b1);
      double r = fmax(b2,b3), s2 = fmin(b2,b3);
      double r1 = fmax(p,r), rx = fmin(p,r), ry = fmax(q,s2);
      double r2 = fmax(rx,ry), r3 = fmin(rx,ry);
      double gsc = r1 + r2;
      g23 = r2 - r3;                                  // group 2nd/3rd boundary
      const int g = e >> 2;
      int grank = 0;
      #pragma unroll
      for (int h = 0; h < 8; ++h){
        double gh = __shfl(gsc, h*4);
        grank += (gh > gsc) || (gh == gsc && h < g);
      }
      double mi = (grank < 3) ? gsc :  1e300;
      double mo = (grank < 3) ? -1e300 : gsc;
      #pragma unroll
      for (int off = 16; off; off >>= 1){
        mi = fmin(mi, __shfl_xor(mi, off));
        mo = fmax(mo, __shfl_xor(mo, off));
      }
      g34 = mi - mo;                                  // group 3rd/4th boundary
      double v = (grank < 3) ? sc_ : 0.0;
      wsum = 0.0;
      double bv4 = 0.0;
      #pragma unroll
      for (int rr = 0; rr < 5; ++rr){
        double bv = v; int bi = e;
        #pragma unroll
        for (int off = 16; off; off >>= 1){
          double ov = __shfl_xor(bv, off);
          int    oi = __shfl_xor(bi, off);
          if (ov > bv || (ov == bv && oi < bi)){ bv = ov; bi = oi; }
        }
        if (rr < 4){
          idxr[rr] = bi;
          double sv = __shfl(s_, bi);
          svalr[rr] = sv; wsum += sv;
          if (e == bi) v = -1.0e300;
          bv4 = bv;
        } else {
          g45 = bv4 - bv;                             // expert 4th/5th boundary
        }
      }
    };
    decide(s, sc);
    const bool fl = (g23 < 8.0*(double)errS) || (g45 < 8.0*(double)errS) ||
                    (g34 < 16.0*(double)errS);
    if (__any(fl ? 1 : 0)){
      // fp64 redo (rare): float4-unrolled loads -> one latency window per expert
      double myL = 0.0;
      const float4* xr4 = (const float4*)&xs[t][0];
      for (int ei2 = 0; ei2 < NEXP; ++ei2){
        const float4* wr4 = (const float4*)&rw[(size_t)ei2*DIM];
        double acc = 0.0;
        #pragma unroll
        for (int it = 0; it < 8; ++it){
          const int d4 = it*64 + lane;
          float4 w4 = wr4[d4];
          float4 v4 = xr4[d4];
          acc += (double)v4.x*(double)w4.x + (double)v4.y*(double)w4.y
               + (double)v4.z*(double)w4.z + (double)v4.w*(double)w4.w;
        }
        #pragma unroll
        for (int off = 32; off; off >>= 1) acc += __shfl_down(acc, off);
        acc = __shfl(acc, 0);
        if (e == ei2) myL = acc;
      }
      s  = 1.0 / (1.0 + exp(-myL));
      sc = s + (double)eb[e];
      decide(s, sc);
    }
    if (lane == 0){
      const int gt = tb + t;
      #pragma unroll
      for (int r = 0; r < 4; ++r){
        tki[gt*4 + r] = idxr[r];
        tkw[gt*4 + r] = (float)(svalr[r] / (wsum + 1e-20) * 2.5);
      }
    }
  }

  // ---- fused shared-weight fp32->bf16 (1024 blocks x 1536 chunks exact cover) ----
  #pragma unroll
  for (int i = 0; i < 6; ++i){
    int g = blockIdx.x*1536 + i*256 + tid;
    int local = g & 524287;
    int sel = g >> 19;
    const float* src = (sel == 0) ? sg : (sel == 1) ? su : sd;
    unsigned short* dst = (sel == 0) ? sgb : (sel == 1) ? sub_ : sdb;
    const float4 a = *(const float4*)&src[(size_t)local*8];
    const float4 b = *(const float4*)&src[(size_t)local*8 + 4];
    uint4 v;
    v.x = f2bf(a.x) | (f2bf(a.y) << 16);
    v.y = f2bf(a.z) | (f2bf(a.w) << 16);
    v.z = f2bf(b.x) | (f2bf(b.y) << 16);
    v.w = f2bf(b.z) | (f2bf(b.w) << 16);
    *(uint4*)&dst[(size_t)local*8] = v;
  }
}

// ---------- dispatch v2: one block per expert, two-phase parallel rank scan ----------
__global__ __launch_bounds__(1024) void dispatch_k(const int* __restrict__ tki,
                                                   const float* __restrict__ tkw,
                                                   int* __restrict__ stok,
                                                   float* __restrict__ sw){
  const int e    = blockIdx.x;
  const int tid  = threadIdx.x;
  const int lane = tid & 63, w = tid >> 6;            // 16 waves
  __shared__ int cnt[16], basep[16], tot;

  int ex[16];
  #pragma unroll
  for (int it = 0; it < 16; ++it)
    ex[it] = tki[w*1024 + it*64 + lane];              // 16 independent loads
  int c = 0;
  #pragma unroll
  for (int it = 0; it < 16; ++it)
    c += __popcll(__ballot(ex[it] == e));
  if (lane == 0) cnt[w] = c;
  __syncthreads();
  if (tid == 0){
    int run = 0;
    #pragma unroll
    for (int i = 0; i < 16; ++i){ basep[i] = run; run += cnt[i]; }
    tot = (run < CAP) ? run : CAP;
  }
  __syncthreads();

  int base = basep[w];
  #pragma unroll
  for (int it = 0; it < 16; ++it){
    const int idx = w*1024 + it*64 + lane;
    const bool m = (ex[it] == e);
    unsigned long long mk = __ballot(m);
    int pos = base + __popcll(mk & ((1ull << lane) - 1ull));
    if (m && pos < CAP){
      stok[e*CAP + pos] = idx >> 2;
      sw[e*CAP + pos]   = tkw[idx];
    }
    base += __popcll(mk);
  }

  for (int s2 = tot + tid; s2 < CAP; s2 += 1024){
    stok[e*CAP + s2] = 0;
    sw[e*CAP + s2]   = 0.f;
  }
}

// ---------- MFMA GEMM ----------
// MODE 0 EGU: 8 waves, 3-buf counted-vmcnt; A gathered; B fp32 [K,1024]; BN=64+64; grid 512.
// MODE 1 EDN: 8 waves, 3-buf; atomic scatter; B fp32 [K,2048]; BN=128; grid 512.
// MODE 2 SGU: 16 waves (1024 thr), BM=256, BN=128+128, 2-buf 1-barrier/step; grid 256.
// MODE 3 SDN: 16 waves, BM=256, BN=128, 2-buf; plain f32 store; grid 256.
template<int MODE>
__global__ __launch_bounds__((MODE <= 1) ? 512 : 1024, (MODE <= 1) ? 2 : 4)
void gemm9_k(const unsigned short* __restrict__ Ab,
             const void* __restrict__ B0v, const void* __restrict__ B1v,
             void* __restrict__ Co,
             const int* __restrict__ stok, const float* __restrict__ sw){
  constexpr int BM   = (MODE < 2) ? 160 : 256;
  constexpr int APL  = BM/16;                       // 10,10,16,16
  constexpr int FM   = (MODE < 2) ? 5 : 4;          // m-frags per wave
  constexpr int KK   = (MODE == 1) ? ISZ : DIM;
  constexpr int BPL  = (MODE == 2) ? 16 : 8;        // B planes
  constexpr int NBF  = (MODE == 2) ? 4 : 2;         // B frags per wave
  constexpr int TPL  = APL + BPL;                   // 18,18,32,24
  constexpr int NT   = KK/32;
  constexpr int LDB  = (MODE == 0) ? ISZ : DIM;     // fp32 B n-stride
  constexpr int LDC  = (MODE == 0) ? ISZ : ((MODE == 2) ? ISH : DIM);
  constexpr int NWV  = (MODE <= 1) ? 8 : 16;        // waves per block
  constexpr int SAIT = 2;
  constexpr int NBUF = (MODE <= 1) ? 3 : 2;

  __shared__ uint4 lds[NBUF][TPL*64];

  const int tid  = threadIdx.x;
  const int lane = tid & 63, wid = tid >> 6;

  const int bid = blockIdx.x;
  int e = 0, mb = 0, nb;
  if constexpr (MODE < 2){
    // XCD-aware: bid%8 -> experts 4x..4x+3 on one XCD (A-tile L2 reuse); 16 nblks
    const int x = bid & 7, s = bid >> 3;
    e  = x*4 + (s & 3);
    nb = (s >> 2) * (MODE == 0 ? 64 : 128);
  } else {
    mb = (bid & 15)*256; nb = (bid >> 4)*128;       // same-n adjacent (B L2-hot)
  }

  // ---- gload plane pointers (A always; B too for MODE>=2) ----
  const unsigned short* gptr[SAIT];
  #pragma unroll
  for (int i = 0; i < SAIT; ++i){
    int p = wid + i*NWV;
    int pp = (p < ((MODE >= 2) ? TPL : APL)) ? p : 0;
    if (pp < APL){
      int r = pp*16 + (lane & 15);
      int row;
      if constexpr (MODE == 0)      row = stok[e*CAP + r];
      else if constexpr (MODE == 1) row = e*CAP + r;
      else                          row = mb + r;
      gptr[i] = Ab + (size_t)row*KK + (lane >> 4)*8;
    } else {
      int q = pp - APL;
      const unsigned short* src = (const unsigned short*)B0v;
      int n;
      if constexpr (MODE == 2){ if (q & 1) src = (const unsigned short*)B1v;
                                n = nb + (q >> 1)*16 + (lane & 15); }
      else                    { n = nb + q*16 + (lane & 15); }
      gptr[i] = src + (size_t)n*KK + (lane >> 4)*8;
    }
  }
  auto stageG = [&](int k0, int buf){
    char* base = (char*)&lds[buf][0];
    #pragma unroll
    for (int i = 0; i < SAIT; ++i){
      int p = wid + i*NWV;
      if (p < ((MODE >= 2) ? TPL : APL))
        GLOAD16(gptr[i] + k0, base + p*1024);
    }
  };

  // ---- fp32 B reg-staging (MODE<=1): thread = (plane, col, k-oct) ----
  const int bq   = (tid & 127) >> 4;    // plane 0..7
  const int bcl  = tid & 15;            // col within plane
  const int boct = tid >> 7;            // k-oct 0..3
  const float* bkn = nullptr;
  if constexpr (MODE == 0){
    const float* src = (const float*)((bq & 1) ? B1v : B0v);
    int n0 = nb + (bq >> 1)*16 + bcl;
    bkn = src + (size_t)e*KK*LDB + (size_t)boct*8*LDB + n0;
  } else if constexpr (MODE == 1){
    bkn = (const float*)B0v + (size_t)e*KK*LDB + (size_t)boct*8*LDB + (nb + bq*16 + bcl);
  }
  auto loadB = [&](int k0, float (&br)[8]){
    const float* p = bkn + (size_t)k0*LDB;
    #pragma unroll
    for (int j = 0; j < 8; ++j) br[j] = p[(size_t)j*LDB];
  };
  auto writeB = [&](int buf, const float (&br)[8]){
    uint4 v;
    v.x = f2bf(br[0]) | (f2bf(br[1]) << 16);
    v.y = f2bf(br[2]) | (f2bf(br[3]) << 16);
    v.z = f2bf(br[4]) | (f2bf(br[5]) << 16);
    v.w = f2bf(br[6]) | (f2bf(br[7]) << 16);
    *(uint4*)((char*)&lds[buf][0] + (APL + bq)*1024 + boct*256 + bcl*16) = v;
  };

  // counted waits (MODE<=1 only)
  auto waitK = [&]{
    if constexpr (MODE <= 1){
      if (wid < 2) asm volatile("s_waitcnt vmcnt(10)" ::: "memory");
      else         asm volatile("s_waitcnt vmcnt(9)"  ::: "memory");
      asm volatile("s_waitcnt lgkmcnt(0)" ::: "memory");
    }
  };

  // ---- compute-side assignment: MODE<=1 2m x 4n; MODE>=2 4m x 4n ----
  const int wmp = (wid >> 2) * FM;
  const int wq  = wid & 3;
  f32x4 acc[FM][NBF];
  #pragma unroll
  for (int i = 0; i < FM; ++i)
    #pragma unroll
    for (int j = 0; j < NBF; ++j) acc[i][j] = f32x4{0,0,0,0};

  if constexpr (MODE <= 1){
    float brA[8], brB[8];
    // ---- prologue: two stages in flight ----
    stageG(0, 0);
    loadB(0, brA);
    stageG(32, 1);
    loadB(32, brB); writeB(0, brA);
    waitK();
    __builtin_amdgcn_s_barrier();

    int cons = 0;
    auto step = [&](int t, float (&brW)[8], float (&brL)[8]){
      const int stg = (cons >= 1) ? cons - 1 : 2;         // (cons+2)%3
      const int nxt = (cons == 2) ? 0 : cons + 1;
      if (t + 2 < NT){
        stageG((t+2)*32, stg);
        loadB((t+2)*32, brL);
      }
      __builtin_amdgcn_sched_barrier(0);                  // pin issues early
      const char* L = (const char*)&lds[cons][0];
      bf16x8 af[FM], bfr[NBF];
      #pragma unroll
      for (int i = 0; i < FM; ++i)
        af[i] = *(const bf16x8*)(L + (wmp + i)*1024 + lane*16);
      #pragma unroll
      for (int j = 0; j < NBF; ++j)
        bfr[j] = *(const bf16x8*)(L + (APL + wq*NBF + j)*1024 + lane*16);
      __builtin_amdgcn_s_setprio(1);
      #pragma unroll
      for (int i = 0; i < FM; ++i)
        #pragma unroll
        for (int j = 0; j < NBF; ++j)
          acc[i][j] = __builtin_amdgcn_mfma_f32_16x16x32_bf16(af[i], bfr[j], acc[i][j], 0, 0, 0);
      __builtin_amdgcn_s_setprio(0);
      if (t + 1 < NT) writeB(nxt, brW);
      if (t + 2 < NT){
        waitK();                                          // leave t+2 batch in flight
      } else if (t == NT - 2){
        asm volatile("s_waitcnt vmcnt(0)" ::: "memory");
        asm volatile("s_waitcnt lgkmcnt(0)" ::: "memory");
      }
      if (t < NT - 1) __builtin_amdgcn_s_barrier();
      cons = nxt;
    };

    for (int t2 = 0; t2 < NT/2; ++t2){
      step(2*t2,     brB, brA);
      step(2*t2 + 1, brA, brB);
    }
  } else {
    // ---- 2-buf, one barrier per step (T3 minimum 2-phase, 16 waves) ----
    stageG(0, 0);
    for (int t = 0; t < NT; ++t){
      asm volatile("s_waitcnt vmcnt(0)" ::: "memory");    // stage(t) landed
      __builtin_amdgcn_s_barrier();                       // all waves: stage(t) done, prev reads retired
      if (t + 1 < NT) stageG((t+1)*32, (t+1)&1);          // prefetch under this step's compute
      __builtin_amdgcn_sched_barrier(0);
      const char* L = (const char*)&lds[t & 1][0];
      bf16x8 af[FM], bfr[NBF];
      #pragma unroll
      for (int i = 0; i < FM; ++i)
        af[i] = *(const bf16x8*)(L + (wmp + i)*1024 + lane*16);
      #pragma unroll
      for (int j = 0; j < NBF; ++j)
        bfr[j] = *(const bf16x8*)(L + (APL + wq*NBF + j)*1024 + lane*16);
      __builtin_amdgcn_s_setprio(1);
      #pragma unroll
      for (int i = 0; i < FM; ++i)
        #pragma unroll
        for (int j = 0; j < NBF; ++j)
          acc[i][j] = __builtin_amdgcn_mfma_f32_16x16x32_bf16(af[i], bfr[j], acc[i][j], 0, 0, 0);
      __builtin_amdgcn_s_setprio(0);
    }
  }

  // ---- epilogue ----
  const int cl = lane & 15, rg = (lane >> 4)*4;
  #pragma unroll
  for (int i = 0; i < FM; ++i){
    #pragma unroll
    for (int r = 0; r < 4; ++r){
      const int m = wmp*16 + i*16 + rg + r;
      if constexpr (MODE == 0){
        float g = acc[i][0][r], u = acc[i][1][r];
        float h = g / (1.f + __expf(-g)) * u;
        int gcol = nb + wq*16 + cl;
        ((unsigned short*)Co)[(size_t)(e*CAP + m)*LDC + gcol] = (unsigned short)f2bf(h);
      } else if constexpr (MODE == 2){
        #pragma unroll
        for (int jj = 0; jj < 2; ++jj){
          float g = acc[i][jj*2][r], u = acc[i][jj*2+1][r];
          float h = g / (1.f + __expf(-g)) * u;
          int gcol = nb + wq*32 + jj*16 + cl;
          ((unsigned short*)Co)[(size_t)(mb + m)*LDC + gcol] = (unsigned short)f2bf(h);
        }
      } else if constexpr (MODE == 1){
        const int slot = e*CAP + m;
        float w = sw[slot];
        if (w != 0.f){
          int tok = stok[slot];
          #pragma unroll
          for (int j = 0; j < 2; ++j){
            int c = nb + wq*32 + j*16 + cl;
            atomicAdd(&((float*)Co)[(size_t)tok*DIM + c], w * acc[i][j][r]);
          }
        }
      } else {
        #pragma unroll
        for (int j = 0; j < 2; ++j){
          int c = nb + wq*32 + j*16 + cl;
          ((float*)Co)[(size_t)(mb + m)*DIM + c] = acc[i][j][r];
        }
      }
    }
  }
}

extern "C" void kernel_launch(void* const* d_in, const int* in_sizes, int n_in,
                              void* d_out, int out_size, void* d_ws, size_t ws_size,
                              hipStream_t stream){
  const float* x  = (const float*)d_in[0];
  const float* rw = (const float*)d_in[1];
  const float* eb = (const float*)d_in[2];
  const float* wg = (const float*)d_in[3];
  const float* wu = (const float*)d_in[4];
  const float* wd = (const float*)d_in[5];
  const float* sg = (const float*)d_in[6];
  const float* su = (const float*)d_in[7];
  const float* sd = (const float*)d_in[8];
  float* out = (float*)d_out;

  char* ws = (char*)d_ws;
  unsigned short* xbf = (unsigned short*)ws; ws += (size_t)T_TOK*DIM*2;
  unsigned short* hsh = (unsigned short*)ws; ws += (size_t)T_TOK*ISH*2;
  unsigned short* hex = (unsigned short*)ws; ws += (size_t)ECAP*ISZ*2;
  unsigned short* sgb = (unsigned short*)ws; ws += (size_t)ISH*DIM*2;
  unsigned short* sub = (unsigned short*)ws; ws += (size_t)ISH*DIM*2;
  unsigned short* sdb = (unsigned short*)ws; ws += (size_t)DIM*ISH*2;
  int*   tki  = (int*)ws;   ws += (size_t)T_TOK*TOPK*4;
  float* tkw  = (float*)ws; ws += (size_t)T_TOK*TOPK*4;
  int*   stok = (int*)ws;   ws += (size_t)ECAP*4;
  float* sw   = (float*)ws; ws += (size_t)ECAP*4;

  // router (fp32 fast-path, vectorized; certified fp64 fallback; emits xbf + bf16 weights)
  router_k<<<T_TOK/4, 256, 0, stream>>>(x, rw, eb, tki, tkw, xbf,
                                        sg, su, sd, sgb, sub, sdb);
  // dispatch v2: one block per expert, two-phase parallel scan
  dispatch_k<<<NEXP, 1024, 0, stream>>>(tki, tkw, stok, sw);

  // shared MLP: gate+up+silu -> hsh ; down -> out (16-wave 2-buf blocks)
  gemm9_k<2><<<256, 1024, 0, stream>>>(xbf, sgb, sub, hsh, nullptr, nullptr);
  gemm9_k<3><<<256, 1024, 0, stream>>>(hsh, sdb, nullptr, out, nullptr, nullptr);

  // routed experts (B = fp32 weights read once, reg-transposed), 2 blocks/CU
  gemm9_k<0><<<512, 512, 0, stream>>>(xbf, wg, wu, hex, stok, sw);
  gemm9_k<1><<<512, 512, 0, stream>>>(hex, wd, nullptr, out, stok, sw);
}

// Round 19
// 424.877 us; speedup vs baseline: 1.0480x; 1.0480x over previous
//
#include <hip/hip_runtime.h>
#include <math.h>

// ---------- config ----------
#define T_TOK 4096
#define DIM   2048
#define NEXP  32
#define TOPK  4
#define CAP   160          // ceil(1.25*4096/32)
#define ECAP  (NEXP*CAP)   // 5120
#define ISZ   1024         // moe intermediate
#define ISH   2048         // shared intermediate (I*NSH)

typedef short bf16x8 __attribute__((ext_vector_type(8)));
typedef float f32x4  __attribute__((ext_vector_type(4)));

__device__ __forceinline__ unsigned int f2bf(float f){
  union { float f; unsigned int u; } v; v.f = f;
  return (v.u + 0x7fffu + ((v.u >> 16) & 1u)) >> 16;   // RNE
}

// async global->LDS, 16B/lane; LDS base wave-uniform (HW adds lane*16), global addr per-lane
#define GLOAD16(g, l) __builtin_amdgcn_global_load_lds( \
    (const __attribute__((address_space(1))) unsigned int*)(g), \
    (__attribute__((address_space(3))) unsigned int*)(l), 16, 0, 0)

// ---------- router: fp32 fast-path logits + certified margins; fp64 fallback ----------
__global__ __launch_bounds__(256) void router_k(const float* __restrict__ x,
                                                const float* __restrict__ rw,
                                                const float* __restrict__ eb,
                                                int* __restrict__ tki,
                                                float* __restrict__ tkw,
                                                unsigned short* __restrict__ xbf,
                                                const float* __restrict__ sg,
                                                const float* __restrict__ su,
                                                const float* __restrict__ sd,
                                                unsigned short* __restrict__ sgb,
                                                unsigned short* __restrict__ sub_,
                                                unsigned short* __restrict__ sdb){
  __shared__ float xs[4][DIM];
  __shared__ float lsh[4][NEXP];   // fp32 logits
  __shared__ float wsh[NEXP];      // ||w_e||^2
  __shared__ float xq[4];          // ||x_t||^2
  const int tb = blockIdx.x * 4;
  const int tid = threadIdx.x;
  for (int i = tid; i < 4*(DIM/4); i += 256){
    int t = i >> 9, c = (i & 511) << 2;
    float4 f = *(const float4*)&x[(size_t)(tb + t)*DIM + c];
    *(float4*)&xs[t][c] = f;
    uint2 w;
    w.x = f2bf(f.x) | (f2bf(f.y) << 16);
    w.y = f2bf(f.z) | (f2bf(f.w) << 16);
    *(uint2*)&xbf[(size_t)(tb + t)*DIM + c] = w;     // fused x -> bf16
  }
  __syncthreads();
  const int lane = tid & 63, wv = tid >> 6;

  // ---- fp32 dot phase: wave wv = experts wv*8..+7; float4-vectorized, unrolled ----
  for (int ei = 0; ei < 8; ++ei){
    const int e = wv*8 + ei;
    const float4* wr4 = (const float4*)&rw[(size_t)e*DIM];
    float a0=0.f,a1=0.f,a2=0.f,a3=0.f,w2=0.f;
    float x20=0.f,x21=0.f,x22=0.f,x23=0.f;
    const bool doX2 = (wv == 0) && (ei == 0);
    #pragma unroll
    for (int it = 0; it < 8; ++it){
      const int d4 = it*64 + lane;
      float4 w4 = wr4[d4];
      float4 v0 = *(const float4*)&xs[0][d4*4];
      float4 v1 = *(const float4*)&xs[1][d4*4];
      float4 v2 = *(const float4*)&xs[2][d4*4];
      float4 v3 = *(const float4*)&xs[3][d4*4];
      a0 = fmaf(v0.x,w4.x,fmaf(v0.y,w4.y,fmaf(v0.z,w4.z,fmaf(v0.w,w4.w,a0))));
      a1 = fmaf(v1.x,w4.x,fmaf(v1.y,w4.y,fmaf(v1.z,w4.z,fmaf(v1.w,w4.w,a1))));
      a2 = fmaf(v2.x,w4.x,fmaf(v2.y,w4.y,fmaf(v2.z,w4.z,fmaf(v2.w,w4.w,a2))));
      a3 = fmaf(v3.x,w4.x,fmaf(v3.y,w4.y,fmaf(v3.z,w4.z,fmaf(v3.w,w4.w,a3))));
      w2 = fmaf(w4.x,w4.x,fmaf(w4.y,w4.y,fmaf(w4.z,w4.z,fmaf(w4.w,w4.w,w2))));
      if (doX2){
        x20 = fmaf(v0.x,v0.x,fmaf(v0.y,v0.y,fmaf(v0.z,v0.z,fmaf(v0.w,v0.w,x20))));
        x21 = fmaf(v1.x,v1.x,fmaf(v1.y,v1.y,fmaf(v1.z,v1.z,fmaf(v1.w,v1.w,x21))));
        x22 = fmaf(v2.x,v2.x,fmaf(v2.y,v2.y,fmaf(v2.z,v2.z,fmaf(v2.w,v2.w,x22))));
        x23 = fmaf(v3.x,v3.x,fmaf(v3.y,v3.y,fmaf(v3.z,v3.z,fmaf(v3.w,v3.w,x23))));
      }
    }
    #pragma unroll
    for (int off = 32; off; off >>= 1){
      a0 += __shfl_down(a0, off); a1 += __shfl_down(a1, off);
      a2 += __shfl_down(a2, off); a3 += __shfl_down(a3, off);
      w2 += __shfl_down(w2, off);
      if (doX2){
        x20 += __shfl_down(x20, off); x21 += __shfl_down(x21, off);
        x22 += __shfl_down(x22, off); x23 += __shfl_down(x23, off);
      }
    }
    if (lane == 0){
      lsh[0][e] = a0; lsh[1][e] = a1; lsh[2][e] = a2; lsh[3][e] = a3;
      wsh[e] = w2;
      if (doX2){ xq[0]=x20; xq[1]=x21; xq[2]=x22; xq[3]=x23; }
    }
  }
  __syncthreads();

  // ---- wave-parallel top-k with certified margins: wave wv = token wv; lane e = expert ----
  {
    const int t = wv;
    const int e = lane & 31;
    const float Lf = lsh[t][e];
    float errS = 0.25f * sqrtf(xq[t]) * sqrtf(wsh[e]) * 6e-6f;  // score-space bound
    #pragma unroll
    for (int off = 16; off; off >>= 1)
      errS = fmaxf(errS, __shfl_xor(errS, off));

    double s  = 1.0 / (1.0 + exp(-(double)Lf));
    double sc = s + (double)eb[e];

    int idxr[4]; double svalr[4]; double wsum;
    double g23, g34, g45;
    auto decide = [&](double s_, double sc_){
      const int gb = e & ~3;
      double b0 = __shfl(sc_, gb+0), b1 = __shfl(sc_, gb+1);
      double b2 = __shfl(sc_, gb+2), b3 = __shfl(sc_, gb+3);
      double p = fmax(b0,b1), q = fmin(b0,b1);
      double r = fmax(b2,b3), s2 = fmin(b2,b3);
      double r1 = fmax(p,r), rx = fmin(p,r), ry = fmax(q,s2);
      double r2 = fmax(rx,ry), r3 = fmin(rx,ry);
      double gsc = r1 + r2;
      g23 = r2 - r3;                                  // group 2nd/3rd boundary
      const int g = e >> 2;
      int grank = 0;
      #pragma unroll
      for (int h = 0; h < 8; ++h){
        double gh = __shfl(gsc, h*4);
        grank += (gh > gsc) || (gh == gsc && h < g);
      }
      double mi = (grank < 3) ? gsc :  1e300;
      double mo = (grank < 3) ? -1e300 : gsc;
      #pragma unroll
      for (int off = 16; off; off >>= 1){
        mi = fmin(mi, __shfl_xor(mi, off));
        mo = fmax(mo, __shfl_xor(mo, off));
      }
      g34 = mi - mo;                                  // group 3rd/4th boundary
      double v = (grank < 3) ? sc_ : 0.0;
      wsum = 0.0;
      double bv4 = 0.0;
      #pragma unroll
      for (int rr = 0; rr < 5; ++rr){
        double bv = v; int bi = e;
        #pragma unroll
        for (int off = 16; off; off >>= 1){
          double ov = __shfl_xor(bv, off);
          int    oi = __shfl_xor(bi, off);
          if (ov > bv || (ov == bv && oi < bi)){ bv = ov; bi = oi; }
        }
        if (rr < 4){
          idxr[rr] = bi;
          double sv = __shfl(s_, bi);
          svalr[rr] = sv; wsum += sv;
          if (e == bi) v = -1.0e300;
          bv4 = bv;
        } else {
          g45 = bv4 - bv;                             // expert 4th/5th boundary
        }
      }
    };
    decide(s, sc);
    const bool fl = (g23 < 8.0*(double)errS) || (g45 < 8.0*(double)errS) ||
                    (g34 < 16.0*(double)errS);
    if (__any(fl ? 1 : 0)){
      // fp64 redo (rare): float4-unrolled loads -> one latency window per expert
      double myL = 0.0;
      const float4* xr4 = (const float4*)&xs[t][0];
      for (int ei2 = 0; ei2 < NEXP; ++ei2){
        const float4* wr4 = (const float4*)&rw[(size_t)ei2*DIM];
        double acc = 0.0;
        #pragma unroll
        for (int it = 0; it < 8; ++it){
          const int d4 = it*64 + lane;
          float4 w4 = wr4[d4];
          float4 v4 = xr4[d4];
          acc += (double)v4.x*(double)w4.x + (double)v4.y*(double)w4.y
               + (double)v4.z*(double)w4.z + (double)v4.w*(double)w4.w;
        }
        #pragma unroll
        for (int off = 32; off; off >>= 1) acc += __shfl_down(acc, off);
        acc = __shfl(acc, 0);
        if (e == ei2) myL = acc;
      }
      s  = 1.0 / (1.0 + exp(-myL));
      sc = s + (double)eb[e];
      decide(s, sc);
    }
    if (lane == 0){
      const int gt = tb + t;
      #pragma unroll
      for (int r = 0; r < 4; ++r){
        tki[gt*4 + r] = idxr[r];
        tkw[gt*4 + r] = (float)(svalr[r] / (wsum + 1e-20) * 2.5);
      }
    }
  }

  // ---- fused shared-weight fp32->bf16 (1024 blocks x 1536 chunks exact cover) ----
  #pragma unroll
  for (int i = 0; i < 6; ++i){
    int g = blockIdx.x*1536 + i*256 + tid;
    int local = g & 524287;
    int sel = g >> 19;
    const float* src = (sel == 0) ? sg : (sel == 1) ? su : sd;
    unsigned short* dst = (sel == 0) ? sgb : (sel == 1) ? sub_ : sdb;
    const float4 a = *(const float4*)&src[(size_t)local*8];
    const float4 b = *(const float4*)&src[(size_t)local*8 + 4];
    uint4 v;
    v.x = f2bf(a.x) | (f2bf(a.y) << 16);
    v.y = f2bf(a.z) | (f2bf(a.w) << 16);
    v.z = f2bf(b.x) | (f2bf(b.y) << 16);
    v.w = f2bf(b.z) | (f2bf(b.w) << 16);
    *(uint4*)&dst[(size_t)local*8] = v;
  }
}

// ---------- dispatch v2: one block per expert, two-phase parallel rank scan ----------
__global__ __launch_bounds__(1024) void dispatch_k(const int* __restrict__ tki,
                                                   const float* __restrict__ tkw,
                                                   int* __restrict__ stok,
                                                   float* __restrict__ sw){
  const int e    = blockIdx.x;
  const int tid  = threadIdx.x;
  const int lane = tid & 63, w = tid >> 6;            // 16 waves
  __shared__ int cnt[16], basep[16], tot;

  int ex[16];
  #pragma unroll
  for (int it = 0; it < 16; ++it)
    ex[it] = tki[w*1024 + it*64 + lane];              // 16 independent loads
  int c = 0;
  #pragma unroll
  for (int it = 0; it < 16; ++it)
    c += __popcll(__ballot(ex[it] == e));
  if (lane == 0) cnt[w] = c;
  __syncthreads();
  if (tid == 0){
    int run = 0;
    #pragma unroll
    for (int i = 0; i < 16; ++i){ basep[i] = run; run += cnt[i]; }
    tot = (run < CAP) ? run : CAP;
  }
  __syncthreads();

  int base = basep[w];
  #pragma unroll
  for (int it = 0; it < 16; ++it){
    const int idx = w*1024 + it*64 + lane;
    const bool m = (ex[it] == e);
    unsigned long long mk = __ballot(m);
    int pos = base + __popcll(mk & ((1ull << lane) - 1ull));
    if (m && pos < CAP){
      stok[e*CAP + pos] = idx >> 2;
      sw[e*CAP + pos]   = tkw[idx];
    }
    base += __popcll(mk);
  }

  for (int s2 = tot + tid; s2 < CAP; s2 += 1024){
    stok[e*CAP + s2] = 0;
    sw[e*CAP + s2]   = 0.f;
  }
}

// ---------- fat-tile 8-wave MFMA GEMM, 3-deep counted-vmcnt pipeline + T5 setprio ----------
// MODE 0 EGU: hex(bf16)=silu(X@Wg)*(X@Wu); A gathered; B fp32 [K,1024]; BN=64+64; grid 512 (2/CU).
// MODE 1 EDN: out += scatter(sw*(hex@Wd)); B fp32 [K,2048]; BN=128; grid 512 (2/CU).
// MODE 2 SGU: hsh=silu(X@sg^T)*(X@su^T); both bf16 gload; BM=256, BN=128+128; grid 256.
// MODE 3 SDN: out(f32 plain)=hsh@sd^T; both bf16 gload; BM=256, BN=128; grid 256.
template<int MODE>
__global__ __launch_bounds__(512, 2)
void gemm9_k(const unsigned short* __restrict__ Ab,
             const void* __restrict__ B0v, const void* __restrict__ B1v,
             void* __restrict__ Co,
             const int* __restrict__ stok, const float* __restrict__ sw){
  constexpr int BM   = (MODE < 2) ? 160 : 256;
  constexpr int APL  = BM/16;                       // 10,10,16,16
  constexpr int FM   = BM/32;                       // 5,5,8,8
  constexpr int KK   = (MODE == 1) ? ISZ : DIM;
  constexpr int BPL  = (MODE == 2) ? 16 : 8;        // B planes
  constexpr int NBF  = BPL/4;                       // B frags per wave (2,2,4,2)
  constexpr int TPL  = APL + BPL;                   // 18,18,32,24
  constexpr int NT   = KK/32;
  constexpr int LDB  = (MODE == 0) ? ISZ : DIM;     // fp32 B n-stride
  constexpr int LDC  = (MODE == 0) ? ISZ : ((MODE == 2) ? ISH : DIM);
  constexpr int SAIT = (MODE >= 2) ? (TPL+7)/8 : 2;

  __shared__ uint4 lds[3][TPL*64];

  const int tid  = threadIdx.x;
  const int lane = tid & 63, wid = tid >> 6;

  const int bid = blockIdx.x;
  int e = 0, mb = 0, nb;
  if constexpr (MODE < 2){
    // XCD-aware: bid%8 -> experts 4x..4x+3 on one XCD (A-tile L2 reuse); 16 nblks
    const int x = bid & 7, s = bid >> 3;
    e  = x*4 + (s & 3);
    nb = (s >> 2) * (MODE == 0 ? 64 : 128);
  } else {
    mb = (bid & 15)*256; nb = (bid >> 4)*128;       // same-n adjacent (B L2-hot)
  }

  // ---- gload plane pointers (A always; B too for MODE>=2) ----
  const unsigned short* gptr[SAIT];
  #pragma unroll
  for (int i = 0; i < SAIT; ++i){
    int p = wid + i*8;
    int pp = (p < ((MODE >= 2) ? TPL : APL)) ? p : 0;
    if (pp < APL){
      int r = pp*16 + (lane & 15);
      int row;
      if constexpr (MODE == 0)      row = stok[e*CAP + r];
      else if constexpr (MODE == 1) row = e*CAP + r;
      else                          row = mb + r;
      gptr[i] = Ab + (size_t)row*KK + (lane >> 4)*8;
    } else {
      int q = pp - APL;
      const unsigned short* src = (const unsigned short*)B0v;
      int n;
      if constexpr (MODE == 2){ if (q & 1) src = (const unsigned short*)B1v;
                                n = nb + (q >> 1)*16 + (lane & 15); }
      else                    { n = nb + q*16 + (lane & 15); }
      gptr[i] = src + (size_t)n*KK + (lane >> 4)*8;
    }
  }
  auto stageG = [&](int k0, int buf){
    char* base = (char*)&lds[buf][0];
    #pragma unroll
    for (int i = 0; i < SAIT; ++i){
      int p = wid + i*8;
      if (p < ((MODE >= 2) ? TPL : APL))
        GLOAD16(gptr[i] + k0, base + p*1024);
    }
  };

  // ---- fp32 B reg-staging (MODE<=1): thread = (plane, col, k-oct) ----
  const int bq   = (tid & 127) >> 4;    // plane 0..7
  const int bcl  = tid & 15;            // col within plane
  const int boct = tid >> 7;            // k-oct 0..3
  const float* bkn = nullptr;
  if constexpr (MODE == 0){
    const float* src = (const float*)((bq & 1) ? B1v : B0v);
    int n0 = nb + (bq >> 1)*16 + bcl;
    bkn = src + (size_t)e*KK*LDB + (size_t)boct*8*LDB + n0;
  } else if constexpr (MODE == 1){
    bkn = (const float*)B0v + (size_t)e*KK*LDB + (size_t)boct*8*LDB + (nb + bq*16 + bcl);
  }
  auto loadB = [&](int k0, float (&br)[8]){
    const float* p = bkn + (size_t)k0*LDB;
    #pragma unroll
    for (int j = 0; j < 8; ++j) br[j] = p[(size_t)j*LDB];
  };
  auto writeB = [&](int buf, const float (&br)[8]){
    uint4 v;
    v.x = f2bf(br[0]) | (f2bf(br[1]) << 16);
    v.y = f2bf(br[2]) | (f2bf(br[3]) << 16);
    v.z = f2bf(br[4]) | (f2bf(br[5]) << 16);
    v.w = f2bf(br[6]) | (f2bf(br[7]) << 16);
    *(uint4*)((char*)&lds[buf][0] + (APL + bq)*1024 + boct*256 + bcl*16) = v;
  };

  // counted waits: K = own loads issued per step
  auto waitK = [&]{
    if constexpr (MODE <= 1){
      if (wid < 2) asm volatile("s_waitcnt vmcnt(10)" ::: "memory");
      else         asm volatile("s_waitcnt vmcnt(9)"  ::: "memory");
      asm volatile("s_waitcnt lgkmcnt(0)" ::: "memory");
    } else if constexpr (MODE == 2){
      asm volatile("s_waitcnt vmcnt(4)" ::: "memory");
    } else {
      asm volatile("s_waitcnt vmcnt(3)" ::: "memory");
    }
  };

  // ---- compute-side assignment: 8 waves = 2m x 4n ----
  const int wmp = (wid >> 2) * FM;
  const int wq  = wid & 3;
  f32x4 acc[FM][NBF];
  #pragma unroll
  for (int i = 0; i < FM; ++i)
    #pragma unroll
    for (int j = 0; j < NBF; ++j) acc[i][j] = f32x4{0,0,0,0};

  float brA[8], brB[8];

  // ---- prologue: two stages in flight ----
  stageG(0, 0);
  if constexpr (MODE <= 1) loadB(0, brA);
  stageG(32, 1);
  if constexpr (MODE <= 1){ loadB(32, brB); writeB(0, brA); }
  waitK();
  __builtin_amdgcn_s_barrier();

  int cons = 0;
  auto step = [&](int t, float (&brW)[8], float (&brL)[8]){
    const int stg = (cons >= 1) ? cons - 1 : 2;         // (cons+2)%3
    const int nxt = (cons == 2) ? 0 : cons + 1;
    if (t + 2 < NT){
      stageG((t+2)*32, stg);
      if constexpr (MODE <= 1) loadB((t+2)*32, brL);
    }
    __builtin_amdgcn_sched_barrier(0);                  // pin issues early
    const char* L = (const char*)&lds[cons][0];
    bf16x8 af[FM], bfr[NBF];
    #pragma unroll
    for (int i = 0; i < FM; ++i)
      af[i] = *(const bf16x8*)(L + (wmp + i)*1024 + lane*16);
    #pragma unroll
    for (int j = 0; j < NBF; ++j)
      bfr[j] = *(const bf16x8*)(L + (APL + wq*NBF + j)*1024 + lane*16);
    __builtin_amdgcn_s_setprio(1);                      // T5 (kept; ~free)
    #pragma unroll
    for (int i = 0; i < FM; ++i)
      #pragma unroll
      for (int j = 0; j < NBF; ++j)
        acc[i][j] = __builtin_amdgcn_mfma_f32_16x16x32_bf16(af[i], bfr[j], acc[i][j], 0, 0, 0);
    __builtin_amdgcn_s_setprio(0);
    if constexpr (MODE <= 1){
      if (t + 1 < NT) writeB(nxt, brW);
    }
    if (t + 2 < NT){
      waitK();                                          // leave t+2 batch in flight
    } else if (t == NT - 2){
      asm volatile("s_waitcnt vmcnt(0)" ::: "memory");
      if constexpr (MODE <= 1) asm volatile("s_waitcnt lgkmcnt(0)" ::: "memory");
    }
    if (t < NT - 1) __builtin_amdgcn_s_barrier();
    cons = nxt;
  };

  for (int t2 = 0; t2 < NT/2; ++t2){
    step(2*t2,     brB, brA);
    step(2*t2 + 1, brA, brB);
  }

  // ---- epilogue ----
  const int cl = lane & 15, rg = (lane >> 4)*4;
  #pragma unroll
  for (int i = 0; i < FM; ++i){
    #pragma unroll
    for (int r = 0; r < 4; ++r){
      const int m = (wid >> 2)*(BM/2) + i*16 + rg + r;
      if constexpr (MODE == 0){
        float g = acc[i][0][r], u = acc[i][1][r];
        float h = g / (1.f + __expf(-g)) * u;
        int gcol = nb + wq*16 + cl;
        ((unsigned short*)Co)[(size_t)(e*CAP + m)*LDC + gcol] = (unsigned short)f2bf(h);
      } else if constexpr (MODE == 2){
        #pragma unroll
        for (int jj = 0; jj < 2; ++jj){
          float g = acc[i][jj*2][r], u = acc[i][jj*2+1][r];
          float h = g / (1.f + __expf(-g)) * u;
          int gcol = nb + wq*32 + jj*16 + cl;
          ((unsigned short*)Co)[(size_t)(mb + m)*LDC + gcol] = (unsigned short)f2bf(h);
        }
      } else if constexpr (MODE == 1){
        const int slot = e*CAP + m;
        float w = sw[slot];
        if (w != 0.f){
          int tok = stok[slot];
          #pragma unroll
          for (int j = 0; j < 2; ++j){
            int c = nb + wq*32 + j*16 + cl;
            atomicAdd(&((float*)Co)[(size_t)tok*DIM + c], w * acc[i][j][r]);
          }
        }
      } else {
        #pragma unroll
        for (int j = 0; j < 2; ++j){
          int c = nb + wq*32 + j*16 + cl;
          ((float*)Co)[(size_t)(mb + m)*DIM + c] = acc[i][j][r];
        }
      }
    }
  }
}

extern "C" void kernel_launch(void* const* d_in, const int* in_sizes, int n_in,
                              void* d_out, int out_size, void* d_ws, size_t ws_size,
                              hipStream_t stream){
  const float* x  = (const float*)d_in[0];
  const float* rw = (const float*)d_in[1];
  const float* eb = (const float*)d_in[2];
  const float* wg = (const float*)d_in[3];
  const float* wu = (const float*)d_in[4];
  const float* wd = (const float*)d_in[5];
  const float* sg = (const float*)d_in[6];
  const float* su = (const float*)d_in[7];
  const float* sd = (const float*)d_in[8];
  float* out = (float*)d_out;

  char* ws = (char*)d_ws;
  unsigned short* xbf = (unsigned short*)ws; ws += (size_t)T_TOK*DIM*2;
  unsigned short* hsh = (unsigned short*)ws; ws += (size_t)T_TOK*ISH*2;
  unsigned short* hex = (unsigned short*)ws; ws += (size_t)ECAP*ISZ*2;
  unsigned short* sgb = (unsigned short*)ws; ws += (size_t)ISH*DIM*2;
  unsigned short* sub = (unsigned short*)ws; ws += (size_t)ISH*DIM*2;
  unsigned short* sdb = (unsigned short*)ws; ws += (size_t)DIM*ISH*2;
  int*   tki  = (int*)ws;   ws += (size_t)T_TOK*TOPK*4;
  float* tkw  = (float*)ws; ws += (size_t)T_TOK*TOPK*4;
  int*   stok = (int*)ws;   ws += (size_t)ECAP*4;
  float* sw   = (float*)ws; ws += (size_t)ECAP*4;

  // router (fp32 fast-path, vectorized; certified fp64 fallback; emits xbf + bf16 weights)
  router_k<<<T_TOK/4, 256, 0, stream>>>(x, rw, eb, tki, tkw, xbf,
                                        sg, su, sd, sgb, sub, sdb);
  // dispatch v2: one block per expert, two-phase parallel scan
  dispatch_k<<<NEXP, 1024, 0, stream>>>(tki, tkw, stok, sw);

  // shared MLP: gate+up+silu -> hsh ; down -> out (plain store initializes d_out)
  gemm9_k<2><<<256, 512, 0, stream>>>(xbf, sgb, sub, hsh, nullptr, nullptr);
  gemm9_k<3><<<256, 512, 0, stream>>>(hsh, sdb, nullptr, out, nullptr, nullptr);

  // routed experts (B = fp32 weights read once, reg-transposed), 2 blocks/CU
  gemm9_k<0><<<512, 512, 0, stream>>>(xbf, wg, wu, hex, stok, sw);
  gemm9_k<1><<<512, 512, 0, stream>>>(hex, wd, nullptr, out, stok, sw);
}